// Round 4
// baseline (7126.237 us; speedup 1.0000x reference)
//
#include <hip/hip_runtime.h>
#include <hip/hip_bf16.h>

// Shapes: H=8, D=128, DH=16, B=32, N=512
constexpr int H_ = 8;
constexpr int D_ = 128;
constexpr int DH_ = 16;
constexpr int B_ = 32;
constexpr int N_ = 512;

constexpr int NQ = 32;    // query rows per attn block
constexpr int MT = 16;    // m-tile (key rows per tile)
constexpr int KSTR = 260; // per-h float stride in Ks/Vs (260%32=4 -> banks 4h..4h+3)

__device__ __forceinline__ void load_lds16(const float* g, float* l) {
  __builtin_amdgcn_global_load_lds(
      (const __attribute__((address_space(1))) void*)g,
      (__attribute__((address_space(3))) void*)l, 16, 0, 0);
}

// ---------------------------------------------------------------------------
// Kernel 1: QKV projection.  grid = (b,h,half) = 512 blocks, 256 threads.
// Q/K/V layout: [H][B][N][DH].  Also zeroes the LN-stat accumulators.
// ---------------------------------------------------------------------------
__global__ __launch_bounds__(256) void qkv_kernel(
    const float* __restrict__ h_fea, const float* __restrict__ Wq,
    const float* __restrict__ Wk, const float* __restrict__ Wv,
    float* __restrict__ Q, float* __restrict__ K, float* __restrict__ V,
    float* __restrict__ stats)
{
  __shared__ float wqs[128 * 16], wks[128 * 16], wvs[128 * 16];
  __shared__ float hs[64 * 132];          // stride 132: f4-aligned, banks r*4+d

  const int t = threadIdx.x;
  const int b = blockIdx.x >> 4;
  const int h = (blockIdx.x >> 1) & 7;
  const int half = blockIdx.x & 1;

  if (blockIdx.x == 0 && t < 64) stats[t] = 0.f;   // zero LN accumulators

  // stage weights once: 512 float4 each
#pragma unroll
  for (int i = 0; i < 2; ++i) {
    int idx4 = t + i * 256;
    ((float4*)wqs)[idx4] = ((const float4*)(Wq + (size_t)h * 2048))[idx4];
    ((float4*)wks)[idx4] = ((const float4*)(Wk + (size_t)h * 2048))[idx4];
    ((float4*)wvs)[idx4] = ((const float4*)(Wv + (size_t)h * 2048))[idx4];
  }

  const int r = t >> 2;                    // 64 rows
  const int e0 = (t & 3) * 4;              // 4 outputs each
  for (int chunk = half * 256; chunk < half * 256 + 256; chunk += 64) {
    __syncthreads();                       // hs safe from previous readers
#pragma unroll
    for (int i = 0; i < 8; ++i) {          // stage 64x128 h_fea chunk
      int idx4 = t + i * 256;
      int rr = idx4 >> 5, c4 = idx4 & 31;
      float4 v = ((const float4*)(h_fea + ((size_t)b * N_ + chunk + rr) * D_))[c4];
      *(float4*)&hs[rr * 132 + c4 * 4] = v;
    }
    __syncthreads();
    float aq0 = 0.f, aq1 = 0.f, aq2 = 0.f, aq3 = 0.f;
    float ak0 = 0.f, ak1 = 0.f, ak2 = 0.f, ak3 = 0.f;
    float av0 = 0.f, av1 = 0.f, av2 = 0.f, av3 = 0.f;
    for (int d = 0; d < D_; ++d) {
      float x = hs[r * 132 + d];
      float4 wq4 = *(const float4*)&wqs[d * 16 + e0];
      float4 wk4 = *(const float4*)&wks[d * 16 + e0];
      float4 wv4 = *(const float4*)&wvs[d * 16 + e0];
      aq0 = fmaf(x, wq4.x, aq0); aq1 = fmaf(x, wq4.y, aq1);
      aq2 = fmaf(x, wq4.z, aq2); aq3 = fmaf(x, wq4.w, aq3);
      ak0 = fmaf(x, wk4.x, ak0); ak1 = fmaf(x, wk4.y, ak1);
      ak2 = fmaf(x, wk4.z, ak2); ak3 = fmaf(x, wk4.w, ak3);
      av0 = fmaf(x, wv4.x, av0); av1 = fmaf(x, wv4.y, av1);
      av2 = fmaf(x, wv4.z, av2); av3 = fmaf(x, wv4.w, av3);
    }
    size_t o = ((size_t)(h * B_ + b) * N_ + chunk + r) * DH_ + e0;
    *(float4*)(Q + o) = make_float4(aq0, aq1, aq2, aq3);
    *(float4*)(K + o) = make_float4(ak0, ak1, ak2, ak3);
    *(float4*)(V + o) = make_float4(av0, av1, av2, av3);
  }
}

// ---------------------------------------------------------------------------
// Kernel 2: fused qk + aux passthrough + score MLP + no-max softmax + PV.
// grid = B*(N/NQ) = 512 blocks (XCD-swizzled), 256 threads (4 waves).
// LDS 53.3 KB + VGPR<=170 -> 3 blocks/CU capacity.
// Ps layout: pair row = m*32 + ((n+m)&31), 9-float stride (conflict-free).
// ---------------------------------------------------------------------------
__global__ __launch_bounds__(256, 3) void attn_kernel(
    const float* __restrict__ Q, const float* __restrict__ K, const float* __restrict__ V,
    const float* __restrict__ aux, const float* __restrict__ W1, const float* __restrict__ b1,
    const float* __restrict__ W2, const float* __restrict__ b2,
    float* __restrict__ heads, float* __restrict__ out_aux)
{
  __shared__ float Ks[2][8 * KSTR];        // 16.6 KB
  __shared__ float Vs[2][8 * KSTR];        // 16.6 KB
  __shared__ float Ps[512 * 9];            // 18.4 KB
  __shared__ float4 W1s4[64];              // [ii][jq]
  __shared__ float4 W2s4[32];              // [j][hq]
  __shared__ float4 b1s4[4];
  __shared__ float4 b2s4[2];

  const int t = threadIdx.x;
  // XCD swizzle: 512 blocks, 64-block contiguous chunk per XCD (4 b's each)
  const int lid = blockIdx.x;
  const int bx = (lid & 7) * 64 + (lid >> 3);
  const int b = bx >> 4;
  const int n0 = (bx & 15) * NQ;

  if (t < 64) W1s4[t] = ((const float4*)W1)[t];
  else if (t < 96) W2s4[t - 64] = ((const float4*)W2)[t - 64];
  else if (t < 100) b1s4[t - 96] = ((const float4*)b1)[t - 96];
  else if (t < 102) b2s4[t - 100] = ((const float4*)b2)[t - 100];

  const int n = t >> 3;                    // 0..31
  const int h = t & 7;
  const int wv = t >> 6, lane = t & 63;
  const int pm = t & 15;                   // MLP: m within tile
  const int pn_base = t >> 4;              // MLP: n base (nn = pn_base + 16*i)

  // Q fragment held in registers for the whole kernel
  const float* qptr = Q + ((size_t)(h * B_ + b) * N_ + n0 + n) * DH_;
  const float4 q0 = ((const float4*)qptr)[0];
  const float4 q1 = ((const float4*)qptr)[1];
  const float4 q2 = ((const float4*)qptr)[2];
  const float4 q3 = ((const float4*)qptr)[3];

  float acc[16];
#pragma unroll
  for (int i = 0; i < 16; ++i) acc[i] = 0.f;
  float l = 0.f;

  // stage K/V tile 0
#pragma unroll
  for (int i = 0; i < 2; ++i) {
    int hh = i * 4 + wv;
    const float* gK = K + ((size_t)(hh * B_ + b) * N_ + 0) * DH_ + lane * 4;
    const float* gV = V + ((size_t)(hh * B_ + b) * N_ + 0) * DH_ + lane * 4;
    load_lds16(gK, &Ks[0][hh * KSTR]);
    load_lds16(gV, &Vs[0][hh * KSTR]);
  }

  for (int tile = 0; tile < N_ / MT; ++tile) {
    const int m0 = tile * MT;
    const int buf = tile & 1;
    __syncthreads();   // prev PV done with Ps/Vs; tile-0/next staging visible

    // ---- aux prefetch into registers (consumed in MLP, drained at next barrier)
    float av[16];
#pragma unroll
    for (int i = 0; i < 2; ++i)
#pragma unroll
      for (int hh = 0; hh < 8; ++hh)
        av[i * 8 + hh] =
            aux[((size_t)(hh * B_ + b) * N_ + n0 + pn_base + 16 * i) * N_ + m0 + pm];

    // stage K/V for NEXT tile
    if (tile + 1 < N_ / MT) {
#pragma unroll
      for (int i = 0; i < 2; ++i) {
        int hh = i * 4 + wv;
        const float* gK = K + ((size_t)(hh * B_ + b) * N_ + m0 + MT) * DH_ + lane * 4;
        const float* gV = V + ((size_t)(hh * B_ + b) * N_ + m0 + MT) * DH_ + lane * 4;
        load_lds16(gK, &Ks[buf ^ 1][hh * KSTR]);
        load_lds16(gV, &Vs[buf ^ 1][hh * KSTR]);
      }
    }

    // ---- qk phase: thread (n,h) computes MT dots ----
#pragma unroll 4
    for (int m = 0; m < MT; ++m) {
      const float4* kp = (const float4*)&Ks[buf][h * KSTR + m * 16];
      float4 k0 = kp[0], k1 = kp[1], k2 = kp[2], k3 = kp[3];
      float d = q0.x * k0.x + q0.y * k0.y + q0.z * k0.z + q0.w * k0.w
              + q1.x * k1.x + q1.y * k1.y + q1.z * k1.z + q1.w * k1.w
              + q2.x * k2.x + q2.y * k2.y + q2.z * k2.z + q2.w * k2.w
              + q3.x * k3.x + q3.y * k3.y + q3.z * k3.z + q3.w * k3.w;
      const int prow = m * 32 + ((n + m) & 31);
      Ps[prow * 9 + h] = d;
    }
    __syncthreads();   // qk visible; aux regs + staged K/V drained

    // ---- MLP phase: 2 pairs per thread, W via float4 broadcast ----
#pragma unroll
    for (int i = 0; i < 2; ++i) {
      const int nn = pn_base + 16 * i;
      const int prow = pm * 32 + ((nn + pm) & 31);
      float c[16];
#pragma unroll
      for (int hh = 0; hh < 8; ++hh) c[hh] = Ps[prow * 9 + hh];
#pragma unroll
      for (int hh = 0; hh < 8; ++hh) c[8 + hh] = av[i * 8 + hh];

      float4 h0 = b1s4[0], h1 = b1s4[1], h2 = b1s4[2], h3 = b1s4[3];
#pragma unroll
      for (int ii = 0; ii < 16; ++ii) {
        const float ci = c[ii];
        float4 w;
        w = W1s4[ii * 4 + 0];
        h0.x = fmaf(ci, w.x, h0.x); h0.y = fmaf(ci, w.y, h0.y);
        h0.z = fmaf(ci, w.z, h0.z); h0.w = fmaf(ci, w.w, h0.w);
        w = W1s4[ii * 4 + 1];
        h1.x = fmaf(ci, w.x, h1.x); h1.y = fmaf(ci, w.y, h1.y);
        h1.z = fmaf(ci, w.z, h1.z); h1.w = fmaf(ci, w.w, h1.w);
        w = W1s4[ii * 4 + 2];
        h2.x = fmaf(ci, w.x, h2.x); h2.y = fmaf(ci, w.y, h2.y);
        h2.z = fmaf(ci, w.z, h2.z); h2.w = fmaf(ci, w.w, h2.w);
        w = W1s4[ii * 4 + 3];
        h3.x = fmaf(ci, w.x, h3.x); h3.y = fmaf(ci, w.y, h3.y);
        h3.z = fmaf(ci, w.z, h3.z); h3.w = fmaf(ci, w.w, h3.w);
      }
      float4 s0 = b2s4[0], s1 = b2s4[1];
#define L2STEP(HV, J) { float hj = fmaxf((HV), 0.f);                         \
      float4 w0 = W2s4[(J) * 2 + 0]; float4 w1 = W2s4[(J) * 2 + 1];          \
      s0.x = fmaf(hj, w0.x, s0.x); s0.y = fmaf(hj, w0.y, s0.y);              \
      s0.z = fmaf(hj, w0.z, s0.z); s0.w = fmaf(hj, w0.w, s0.w);              \
      s1.x = fmaf(hj, w1.x, s1.x); s1.y = fmaf(hj, w1.y, s1.y);              \
      s1.z = fmaf(hj, w1.z, s1.z); s1.w = fmaf(hj, w1.w, s1.w); }
      L2STEP(h0.x, 0)  L2STEP(h0.y, 1)  L2STEP(h0.z, 2)  L2STEP(h0.w, 3)
      L2STEP(h1.x, 4)  L2STEP(h1.y, 5)  L2STEP(h1.z, 6)  L2STEP(h1.w, 7)
      L2STEP(h2.x, 8)  L2STEP(h2.y, 9)  L2STEP(h2.z, 10) L2STEP(h2.w, 11)
      L2STEP(h3.x, 12) L2STEP(h3.y, 13) L2STEP(h3.z, 14) L2STEP(h3.w, 15)
#undef L2STEP
      Ps[prow * 9 + 0] = __expf(s0.x);
      Ps[prow * 9 + 1] = __expf(s0.y);
      Ps[prow * 9 + 2] = __expf(s0.z);
      Ps[prow * 9 + 3] = __expf(s0.w);
      Ps[prow * 9 + 4] = __expf(s1.x);
      Ps[prow * 9 + 5] = __expf(s1.y);
      Ps[prow * 9 + 6] = __expf(s1.z);
      Ps[prow * 9 + 7] = __expf(s1.w);
      // aux copy-out from registers
#pragma unroll
      for (int hh = 0; hh < 8; ++hh)
        out_aux[((size_t)(hh * B_ + b) * N_ + n0 + nn) * N_ + m0 + pm] = av[i * 8 + hh];
    }
    __syncthreads();   // exp(P) visible

    // ---- PV phase: thread (n,h) accumulates ----
#pragma unroll 4
    for (int m = 0; m < MT; ++m) {
      const int prow = m * 32 + ((n + m) & 31);
      float pmv = Ps[prow * 9 + h];
      l += pmv;
      const float4* vp = (const float4*)&Vs[buf][h * KSTR + m * 16];
      float4 v0 = vp[0], v1 = vp[1], v2 = vp[2], v3 = vp[3];
      acc[0] = fmaf(pmv, v0.x, acc[0]);   acc[1] = fmaf(pmv, v0.y, acc[1]);
      acc[2] = fmaf(pmv, v0.z, acc[2]);   acc[3] = fmaf(pmv, v0.w, acc[3]);
      acc[4] = fmaf(pmv, v1.x, acc[4]);   acc[5] = fmaf(pmv, v1.y, acc[5]);
      acc[6] = fmaf(pmv, v1.z, acc[6]);   acc[7] = fmaf(pmv, v1.w, acc[7]);
      acc[8] = fmaf(pmv, v2.x, acc[8]);   acc[9] = fmaf(pmv, v2.y, acc[9]);
      acc[10] = fmaf(pmv, v2.z, acc[10]); acc[11] = fmaf(pmv, v2.w, acc[11]);
      acc[12] = fmaf(pmv, v3.x, acc[12]); acc[13] = fmaf(pmv, v3.y, acc[13]);
      acc[14] = fmaf(pmv, v3.z, acc[14]); acc[15] = fmaf(pmv, v3.w, acc[15]);
    }
  }

  const float inv = 1.0f / l;
  float* hp = heads + ((size_t)b * N_ + n0 + n) * D_ + h * DH_;
  ((float4*)hp)[0] = make_float4(acc[0] * inv, acc[1] * inv, acc[2] * inv, acc[3] * inv);
  ((float4*)hp)[1] = make_float4(acc[4] * inv, acc[5] * inv, acc[6] * inv, acc[7] * inv);
  ((float4*)hp)[2] = make_float4(acc[8] * inv, acc[9] * inv, acc[10] * inv, acc[11] * inv);
  ((float4*)hp)[3] = make_float4(acc[12] * inv, acc[13] * inv, acc[14] * inv, acc[15] * inv);
}

// ---------------------------------------------------------------------------
// Kernel 3: X = heads @ W_out + h_fea, plus LN partial sums via atomics.
// 16 rows per block, 256 threads.
// ---------------------------------------------------------------------------
__global__ __launch_bounds__(256) void wout_kernel(
    const float* __restrict__ heads, const float* __restrict__ Wo,
    const float* __restrict__ h_fea, float* __restrict__ X,
    float* __restrict__ stats)
{
  __shared__ float wos[128 * 128];
  __shared__ float hsd[16][129];
  __shared__ float rs[4], rq[4];
  const int t = threadIdx.x;
  const int r0 = blockIdx.x * 16;
  const int b = r0 >> 9;
#pragma unroll
  for (int i = 0; i < 16; ++i) {
    int idx4 = t + i * 256;
    ((float4*)wos)[idx4] = ((const float4*)Wo)[idx4];
  }
#pragma unroll
  for (int i = 0; i < 2; ++i) {
    int idx4 = t + i * 256;
    int r = idx4 >> 5, c = (idx4 & 31) * 4;
    float4 v = ((const float4*)(heads + (size_t)(r0 + r) * D_))[idx4 & 31];
    hsd[r][c] = v.x; hsd[r][c + 1] = v.y; hsd[r][c + 2] = v.z; hsd[r][c + 3] = v.w;
  }
  __syncthreads();
  const int r = t >> 4, dg = t & 15;
  float acc[8];
#pragma unroll
  for (int i = 0; i < 8; ++i) acc[i] = 0.f;
  for (int k = 0; k < 128; ++k) {
    float hv = hsd[r][k];
#pragma unroll
    for (int i = 0; i < 8; ++i) acc[i] = fmaf(hv, wos[k * 128 + dg + 16 * i], acc[i]);
  }
  size_t base = (size_t)(r0 + r) * D_;
  float s = 0.f, sq = 0.f;
#pragma unroll
  for (int i = 0; i < 8; ++i) {
    int d = dg + 16 * i;
    float v = acc[i] + h_fea[base + d];
    X[base + d] = v;
    s += v; sq += v * v;
  }
#pragma unroll
  for (int o = 32; o; o >>= 1) { s += __shfl_down(s, o); sq += __shfl_down(sq, o); }
  const int wv = t >> 6, lane = t & 63;
  if (lane == 0) { rs[wv] = s; rq[wv] = sq; }
  __syncthreads();
  if (t == 0) {
    s = rs[0] + rs[1] + rs[2] + rs[3];
    sq = rq[0] + rq[1] + rq[2] + rq[3];
    atomicAdd(&stats[b * 2], s);
    atomicAdd(&stats[b * 2 + 1], sq);
  }
}

// ---------------------------------------------------------------------------
// Kernel 4: normalize.  grid = B*8 = 256 blocks, 256 threads.
// ---------------------------------------------------------------------------
__global__ __launch_bounds__(256) void ln_kernel(
    const float* __restrict__ X, const float* __restrict__ stats,
    float* __restrict__ out)
{
  const int b = blockIdx.x >> 3;
  const int sl = blockIdx.x & 7;
  const float M = (float)(N_ * D_);
  const float ts = stats[b * 2], tq = stats[b * 2 + 1];
  const float mean = ts / M;
  const float rstd = rsqrtf((tq - ts * ts / M) / (M - 1.0f) + 1e-5f);
  const size_t base4 = ((size_t)b * (N_ * D_) + sl * 8192) / 4;
  const float4* xp = (const float4*)X + base4;
  float4* op = (float4*)out + base4;
  const int t = threadIdx.x;
#pragma unroll
  for (int i = 0; i < 8; ++i) {
    float4 v = xp[t + i * 256];
    v.x = (v.x - mean) * rstd; v.y = (v.y - mean) * rstd;
    v.z = (v.z - mean) * rstd; v.w = (v.w - mean) * rstd;
    op[t + i * 256] = v;
  }
}

// ---------------------------------------------------------------------------
extern "C" void kernel_launch(void* const* d_in, const int* in_sizes, int n_in,
                              void* d_out, int out_size, void* d_ws, size_t ws_size,
                              hipStream_t stream) {
  const float* h_fea = (const float*)d_in[0];
  const float* aux   = (const float*)d_in[1];
  const float* Wq    = (const float*)d_in[2];
  const float* Wk    = (const float*)d_in[3];
  const float* Wv    = (const float*)d_in[4];
  const float* Wo    = (const float*)d_in[5];
  const float* W1    = (const float*)d_in[6];
  const float* b1    = (const float*)d_in[7];
  const float* W2    = (const float*)d_in[8];
  const float* b2    = (const float*)d_in[9];

  float* out = (float*)d_out;
  float* out_aux = out + (size_t)B_ * N_ * D_;          // output 1: aux passthrough

  float* ws = (float*)d_ws;
  const size_t SEG = (size_t)H_ * B_ * N_ * DH_;        // 2,097,152 floats
  float* Q     = ws;
  float* K     = ws + SEG;
  float* V     = ws + 2 * SEG;
  float* heads = ws + 3 * SEG;                          // [B,N,128]
  float* X     = ws + 4 * SEG;                          // [B,N,128]
  float* stats = ws + 5 * SEG;                          // 64 floats

  qkv_kernel<<<B_ * H_ * 2, 256, 0, stream>>>(h_fea, Wq, Wk, Wv, Q, K, V, stats);
  attn_kernel<<<B_ * (N_ / NQ), 256, 0, stream>>>(Q, K, V, aux, W1, b1, W2, b2,
                                                  heads, out_aux);
  wout_kernel<<<(B_ * N_) / 16, 256, 0, stream>>>(heads, Wo, h_fea, X, stats);
  ln_kernel<<<B_ * 8, 256, 0, stream>>>(X, stats, out);
}